// Round 15
// baseline (86.612 us; speedup 1.0000x reference)
//
#include <hip/hip_runtime.h>
#include <hip/hip_bf16.h>

#define IN_C 64
#define OUT_C 128
#define HID 32
#define KNB 16

typedef __attribute__((ext_vector_type(8))) short short8;
typedef __attribute__((ext_vector_type(4))) float f32x4;
typedef __attribute__((ext_vector_type(4))) int   i32x4;

__device__ __forceinline__ float leaky(float v, float s) { return fmaxf(v, s * v); }

__device__ __forceinline__ unsigned bf16u(float f) {
    __hip_bfloat16 h = __float2bfloat16(f);
    return (unsigned)*reinterpret_cast<unsigned short*>(&h);
}
__device__ __forceinline__ short bf16s(float f) {
    __hip_bfloat16 h = __float2bfloat16(f);
    return *reinterpret_cast<short*>(&h);
}
// non-temporal (evict-first) accesses for single-use streams: keeps h2/pos4/pk
// resident in L2 instead of being evicted by x/out/nbr streaming.
__device__ __forceinline__ f32x4 ntl4(const float* p) {
    return __builtin_nontemporal_load((const f32x4*)p);
}
__device__ __forceinline__ i32x4 ntl4i(const int* p) {
    return __builtin_nontemporal_load((const i32x4*)p);
}
__device__ __forceinline__ int ntli(const int* p) {
    return __builtin_nontemporal_load(p);
}
__device__ __forceinline__ float ntlf(const float* p) {
    return __builtin_nontemporal_load(p);
}
__device__ __forceinline__ void ntsf(float* p, float v) {
    __builtin_nontemporal_store(v, p);
}

// ---------------- K1: h2 pack + pos4 pack + weight pack (fused) -------------
__global__ __launch_bounds__(256) void hid_mfma(
    const float* __restrict__ x, const float* __restrict__ Win,
    const float* __restrict__ bin, const float* __restrict__ pos,
    const float* __restrict__ Wout, const float* __restrict__ Wsc,
    unsigned* __restrict__ h2, float4* __restrict__ pos4,
    short* __restrict__ pk, int P)
{
    int tg = blockIdx.x * 256 + (int)threadIdx.x;   // 4P total threads

    if (tg < P) {
        float4 v;
        v.x = ntlf(pos + 3L * tg + 0); v.y = ntlf(pos + 3L * tg + 1);
        v.z = ntlf(pos + 3L * tg + 2); v.w = 0.f;
        pos4[tg] = v;
    }
    if (tg < 1536) {
        int ks = tg >> 9, rem = tg & 511;
        int nt = rem >> 6, g2 = (rem >> 4) & 3, n2 = rem & 15;
        int col = nt * 16 + n2;
        short8 v;
        #pragma unroll
        for (int e = 0; e < 8; ++e) {
            int row = ks * 32 + 8 * g2 + e;
            float f = (row < 32) ? Wout[row * OUT_C + col]
                                 : Wsc[(row - 32) * OUT_C + col];
            v[e] = bf16s(f);
        }
        *(short8*)(pk + (long)tg * 8) = v;
    }

    int lane = threadIdx.x & 63;
    int widx = __builtin_amdgcn_readfirstlane(threadIdx.x >> 6);
    int wavebase = (blockIdx.x * 4 + widx) * 16;
    if (wavebase >= P) return;
    int n = lane & 15, g = lane >> 4;

    short8 bfr[2][2];
    #pragma unroll
    for (int ks = 0; ks < 2; ++ks)
        #pragma unroll
        for (int nt = 0; nt < 2; ++nt)
            #pragma unroll
            for (int e = 0; e < 8; ++e)
                bfr[ks][nt][e] = bf16s(Win[(ks * 32 + 8 * g + e) * HID + nt * 16 + n]);

    float bv0 = bin[n], bv1 = bin[16 + n];

    const float* xr = x + (long)(wavebase + n) * IN_C;
    short8 a[2];
    #pragma unroll
    for (int ks = 0; ks < 2; ++ks) {
        f32x4 v0 = ntl4(xr + ks * 32 + 8 * g);
        f32x4 v1 = ntl4(xr + ks * 32 + 8 * g + 4);
        a[ks][0] = bf16s(v0[0]); a[ks][1] = bf16s(v0[1]);
        a[ks][2] = bf16s(v0[2]); a[ks][3] = bf16s(v0[3]);
        a[ks][4] = bf16s(v1[0]); a[ks][5] = bf16s(v1[1]);
        a[ks][6] = bf16s(v1[2]); a[ks][7] = bf16s(v1[3]);
    }

    f32x4 acc0 = { bv0, bv0, bv0, bv0 };
    f32x4 acc1 = { bv1, bv1, bv1, bv1 };
    acc0 = __builtin_amdgcn_mfma_f32_16x16x32_bf16(a[0], bfr[0][0], acc0, 0, 0, 0);
    acc0 = __builtin_amdgcn_mfma_f32_16x16x32_bf16(a[1], bfr[1][0], acc0, 0, 0, 0);
    acc1 = __builtin_amdgcn_mfma_f32_16x16x32_bf16(a[0], bfr[0][1], acc1, 0, 0, 0);
    acc1 = __builtin_amdgcn_mfma_f32_16x16x32_bf16(a[1], bfr[1][1], acc1, 0, 0, 0);

    #pragma unroll
    for (int r = 0; r < 4; ++r) {
        unsigned lo = bf16u(leaky(acc0[r], 0.1f));
        unsigned hi = bf16u(leaky(acc1[r], 0.1f));
        h2[(long)(wavebase + 4 * g + r) * 16 + n] = (hi << 16) | lo;
    }
}

// ---------------- K2: edge phase + output GEMV, fused, MFMA ------------------
// = R14 structure (depth-4 pipeline, MFMA column-select conv reduce).
// ONLY change: non-temporal x loads, nbr loads, out stores -> no L2 pollution;
// h2/pos4/pk stay L2-resident (R14 FETCH showed ~70MB h2 re-fetch beyond L2).
__global__ __launch_bounds__(128) __attribute__((amdgpu_waves_per_eu(1, 4)))
void edgeout_mfma(
    const float* __restrict__ x, const float4* __restrict__ pos4,
    const int* __restrict__ nbr, const unsigned* __restrict__ h2,
    const float* __restrict__ Wa, const float* __restrict__ ba,
    const float* __restrict__ Wb, const float* __restrict__ bb,
    const short* __restrict__ pk, const float* __restrict__ bout,
    const float* __restrict__ bsc, float* __restrict__ out, int N, int P)
{
    __shared__ float cbuf[2][32 * 17];     // per-wave conv, transposed [ch][pt]

    int tid = threadIdx.x;
    int lane = tid & 63;
    int widx = __builtin_amdgcn_readfirstlane(tid >> 6);
    int n = lane & 15, g = lane >> 4;
    int wavebase = (blockIdx.x * 2 + widx) * 16;
    if (wavebase >= P) return;
    long pbase = (wavebase >= N) ? (long)N : 0;

    // ---- loop-invariant per-lane preloads ----
    float waX[8], waY[8], waZ[8], bav[8];
    #pragma unroll
    for (int e = 0; e < 8; ++e) {
        int k = 8 * g + e;
        waX[e] = Wa[k]; waY[e] = Wa[HID + k]; waZ[e] = Wa[2 * HID + k];
        bav[e] = ba[k];
    }
    short8 wb0, wb1;
    #pragma unroll
    for (int e = 0; e < 8; ++e) {
        int k = 8 * g + e;
        wb0[e] = bf16s(Wb[k * HID + n]);
        wb1[e] = bf16s(Wb[k * HID + 16 + n]);
    }
    float bb0 = bb[n], bb1 = bb[16 + n];
    float* cb = cbuf[widx];

    // ---- GEMV x-row prefetch (non-temporal: read-once stream) ----
    const float* xr = x + (long)(wavebase + n) * IN_C;
    f32x4 u0 = ntl4(xr + 8 * g);
    f32x4 u1 = ntl4(xr + 8 * g + 4);
    f32x4 u2 = ntl4(xr + 32 + 8 * g);
    f32x4 u3 = ntl4(xr + 32 + 8 * g + 4);

    // ---- conv accumulators: D col = point, row = channel ----
    f32x4 cacc0 = { 0.f, 0.f, 0.f, 0.f };   // channels 4g+r
    f32x4 cacc1 = { 0.f, 0.f, 0.f, 0.f };   // channels 16+4g+r

    // ---- edge phase: 16 points, software-pipelined, fully unrolled ----
    i32x4 qv[KNB]; int qs[KNB];
    float4 pp[KNB], pq[KNB];
    unsigned hv[KNB][4];

#define IDX(i) {                                                        \
        const int* nr = nbr + (long)(wavebase + (i)) * KNB;             \
        qv[i] = ntl4i(nr + 4 * g);                                      \
        qs[i] = ntli(nr + n); }
#define GATHER(i) {                                                     \
        pp[i] = pos4[wavebase + (i)];                                   \
        pq[i] = pos4[pbase + qs[i]];                                    \
        hv[i][0] = h2[(pbase + qv[i].x) * 16 + n];                      \
        hv[i][1] = h2[(pbase + qv[i].y) * 16 + n];                      \
        hv[i][2] = h2[(pbase + qv[i].z) * 16 + n];                      \
        hv[i][3] = h2[(pbase + qv[i].w) * 16 + n]; }

    #pragma unroll
    for (int pt = 0; pt < KNB; ++pt) {
        if (pt == 0) {
            IDX(0) IDX(1) IDX(2) IDX(3) IDX(4)
            GATHER(0) GATHER(1) GATHER(2) GATHER(3)
        }
        if (pt + 5 < KNB) IDX(pt + 5)
        if (pt + 4 < KNB) GATHER(pt + 4)

        float rx = pp[pt].x - pq[pt].x;
        float ry = pp[pt].y - pq[pt].y;
        float rz = pp[pt].z - pq[pt].z;

        short8 af;
        #pragma unroll
        for (int e = 0; e < 8; ++e) {
            float tv = fmaf(rx, waX[e], fmaf(ry, waY[e], fmaf(rz, waZ[e], bav[e])));
            af[e] = bf16s(leaky(tv, 0.1f));
        }

        f32x4 w0 = { bb0, bb0, bb0, bb0 };
        f32x4 w1 = { bb1, bb1, bb1, bb1 };
        w0 = __builtin_amdgcn_mfma_f32_16x16x32_bf16(af, wb0, w0, 0, 0, 0);
        w1 = __builtin_amdgcn_mfma_f32_16x16x32_bf16(af, wb1, w1, 0, 0, 0);

        float hA0 = __uint_as_float(hv[pt][0] << 16), hB0 = __uint_as_float(hv[pt][0] & 0xffff0000u);
        float hA1 = __uint_as_float(hv[pt][1] << 16), hB1 = __uint_as_float(hv[pt][1] & 0xffff0000u);
        float hA2 = __uint_as_float(hv[pt][2] << 16), hB2 = __uint_as_float(hv[pt][2] & 0xffff0000u);
        float hA3 = __uint_as_float(hv[pt][3] << 16), hB3 = __uint_as_float(hv[pt][3] & 0xffff0000u);

        // A-frags: products to bf16, k-slots e=0..3; e=4..7 zero
        short8 am0 = { bf16s(w0[0] * hA0), bf16s(w0[1] * hA1),
                       bf16s(w0[2] * hA2), bf16s(w0[3] * hA3), 0, 0, 0, 0 };
        short8 am1 = { bf16s(w1[0] * hB0), bf16s(w1[1] * hB1),
                       bf16s(w1[2] * hB2), bf16s(w1[3] * hB3), 0, 0, 0, 0 };

        // one-hot B: 1.0 (bf16 0x3F80) in k-slots 0..3 where col n == pt
        short sv = (n == pt) ? (short)0x3F80 : (short)0;
        short8 bsel = { sv, sv, sv, sv, 0, 0, 0, 0 };

        cacc0 = __builtin_amdgcn_mfma_f32_16x16x32_bf16(am0, bsel, cacc0, 0, 0, 0);
        cacc1 = __builtin_amdgcn_mfma_f32_16x16x32_bf16(am1, bsel, cacc1, 0, 0, 0);
    }
#undef IDX
#undef GATHER

    // dump conv to transposed LDS: lane (n,g) reg r -> conv[ch 4g+r][pt n]
    #pragma unroll
    for (int r = 0; r < 4; ++r) {
        cb[(4 * g + r) * 17 + n]      = cacc0[r];
        cb[(16 + 4 * g + r) * 17 + n] = cacc1[r];
    }
    asm volatile("s_waitcnt lgkmcnt(0)" ::: "memory");

    // ---- GEMV phase ----
    short8 a0, a1, a2;
    #pragma unroll
    for (int e = 0; e < 8; ++e)
        a0[e] = bf16s(cb[(8 * g + e) * 17 + n]);   // conv channels (k-step 0)
    a1[0] = bf16s(u0[0]); a1[1] = bf16s(u0[1]); a1[2] = bf16s(u0[2]); a1[3] = bf16s(u0[3]);
    a1[4] = bf16s(u1[0]); a1[5] = bf16s(u1[1]); a1[6] = bf16s(u1[2]); a1[7] = bf16s(u1[3]);
    a2[0] = bf16s(u2[0]); a2[1] = bf16s(u2[1]); a2[2] = bf16s(u2[2]); a2[3] = bf16s(u2[3]);
    a2[4] = bf16s(u3[0]); a2[5] = bf16s(u3[1]); a2[6] = bf16s(u3[2]); a2[7] = bf16s(u3[3]);

    #pragma unroll 2
    for (int nt = 0; nt < 8; ++nt) {
        short8 b0 = *(const short8*)(pk + ((long)(0 * 8 + nt) * 64 + lane) * 8);
        short8 b1 = *(const short8*)(pk + ((long)(1 * 8 + nt) * 64 + lane) * 8);
        short8 b2 = *(const short8*)(pk + ((long)(2 * 8 + nt) * 64 + lane) * 8);
        int o = nt * 16 + n;
        float bv = bout[o] + bsc[o];
        f32x4 acc = { bv, bv, bv, bv };
        acc = __builtin_amdgcn_mfma_f32_16x16x32_bf16(a0, b0, acc, 0, 0, 0);
        acc = __builtin_amdgcn_mfma_f32_16x16x32_bf16(a1, b1, acc, 0, 0, 0);
        acc = __builtin_amdgcn_mfma_f32_16x16x32_bf16(a2, b2, acc, 0, 0, 0);
        #pragma unroll
        for (int r = 0; r < 4; ++r)
            ntsf(out + (long)(wavebase + 4 * g + r) * OUT_C + o, leaky(acc[r], 0.01f));
    }
}

extern "C" void kernel_launch(void* const* d_in, const int* in_sizes, int n_in,
                              void* d_out, int out_size, void* d_ws, size_t ws_size,
                              hipStream_t stream) {
    const float* x    = (const float*)d_in[0];
    const float* pos  = (const float*)d_in[1];
    const int*   nbr  = (const int*)d_in[2];
    const float* Win  = (const float*)d_in[3];
    const float* bin  = (const float*)d_in[4];
    const float* Wa   = (const float*)d_in[5];
    const float* ba   = (const float*)d_in[6];
    const float* Wb   = (const float*)d_in[7];
    const float* bb   = (const float*)d_in[8];
    const float* Wout = (const float*)d_in[9];
    const float* bout = (const float*)d_in[10];
    const float* Wsc  = (const float*)d_in[11];
    const float* bsc  = (const float*)d_in[12];
    float* out = (float*)d_out;

    int P = in_sizes[0] / IN_C;   // B*N = 131072
    int N = P / 2;                // B = 2 per reference

    // ws layout: h2 [P*16 u32] | pos4 [P float4] | pk [1536*8 shorts]
    unsigned* h2  = (unsigned*)d_ws;
    float4*  pos4 = (float4*)((char*)d_ws + (size_t)P * 64);
    short*   pk   = (short*)((char*)d_ws + (size_t)P * 64 + (size_t)P * 16);

    hid_mfma<<<(P + 63) / 64, 256, 0, stream>>>(
        x, Win, bin, pos, Wout, Wsc, h2, pos4, pk, P);
    edgeout_mfma<<<(P + 31) / 32, 128, 0, stream>>>(
        x, pos4, nbr, h2, Wa, ba, Wb, bb, pk, bout, bsc, out, N, P);
}

// Round 16
// 62.394 us; speedup vs baseline: 1.3882x; 1.3882x over previous
//
#include <hip/hip_runtime.h>
#include <hip/hip_bf16.h>

#define IN_C 64
#define OUT_C 128
#define HID 32
#define KNB 16

typedef __attribute__((ext_vector_type(8))) short short8;
typedef __attribute__((ext_vector_type(4))) float f32x4;

__device__ __forceinline__ float leaky(float v, float s) { return fmaxf(v, s * v); }

__device__ __forceinline__ unsigned bf16u(float f) {
    __hip_bfloat16 h = __float2bfloat16(f);
    return (unsigned)*reinterpret_cast<unsigned short*>(&h);
}
__device__ __forceinline__ short bf16s(float f) {
    __hip_bfloat16 h = __float2bfloat16(f);
    return *reinterpret_cast<short*>(&h);
}

// ---------------- K1: h2 pack + pos4 pack + weight pack (fused, = R13) ------
__global__ __launch_bounds__(256) void hid_mfma(
    const float* __restrict__ x, const float* __restrict__ Win,
    const float* __restrict__ bin, const float* __restrict__ pos,
    const float* __restrict__ Wout, const float* __restrict__ Wsc,
    unsigned* __restrict__ h2, float4* __restrict__ pos4,
    short* __restrict__ pk, int P)
{
    int tg = blockIdx.x * 256 + (int)threadIdx.x;   // 4P total threads

    if (tg < P) {
        float4 v;
        v.x = pos[3L * tg + 0]; v.y = pos[3L * tg + 1];
        v.z = pos[3L * tg + 2]; v.w = 0.f;
        pos4[tg] = v;
    }
    if (tg < 1536) {
        int ks = tg >> 9, rem = tg & 511;
        int nt = rem >> 6, g2 = (rem >> 4) & 3, n2 = rem & 15;
        int col = nt * 16 + n2;
        short8 v;
        #pragma unroll
        for (int e = 0; e < 8; ++e) {
            int row = ks * 32 + 8 * g2 + e;
            float f = (row < 32) ? Wout[row * OUT_C + col]
                                 : Wsc[(row - 32) * OUT_C + col];
            v[e] = bf16s(f);
        }
        *(short8*)(pk + (long)tg * 8) = v;
    }

    int lane = threadIdx.x & 63;
    int widx = __builtin_amdgcn_readfirstlane(threadIdx.x >> 6);
    int wavebase = (blockIdx.x * 4 + widx) * 16;
    if (wavebase >= P) return;
    int n = lane & 15, g = lane >> 4;

    short8 bfr[2][2];
    #pragma unroll
    for (int ks = 0; ks < 2; ++ks)
        #pragma unroll
        for (int nt = 0; nt < 2; ++nt)
            #pragma unroll
            for (int e = 0; e < 8; ++e)
                bfr[ks][nt][e] = bf16s(Win[(ks * 32 + 8 * g + e) * HID + nt * 16 + n]);

    float bv0 = bin[n], bv1 = bin[16 + n];

    const float* xr = x + (long)(wavebase + n) * IN_C;
    short8 a[2];
    #pragma unroll
    for (int ks = 0; ks < 2; ++ks) {
        float4 v0 = *(const float4*)(xr + ks * 32 + 8 * g);
        float4 v1 = *(const float4*)(xr + ks * 32 + 8 * g + 4);
        a[ks][0] = bf16s(v0.x); a[ks][1] = bf16s(v0.y);
        a[ks][2] = bf16s(v0.z); a[ks][3] = bf16s(v0.w);
        a[ks][4] = bf16s(v1.x); a[ks][5] = bf16s(v1.y);
        a[ks][6] = bf16s(v1.z); a[ks][7] = bf16s(v1.w);
    }

    f32x4 acc0 = { bv0, bv0, bv0, bv0 };
    f32x4 acc1 = { bv1, bv1, bv1, bv1 };
    acc0 = __builtin_amdgcn_mfma_f32_16x16x32_bf16(a[0], bfr[0][0], acc0, 0, 0, 0);
    acc0 = __builtin_amdgcn_mfma_f32_16x16x32_bf16(a[1], bfr[1][0], acc0, 0, 0, 0);
    acc1 = __builtin_amdgcn_mfma_f32_16x16x32_bf16(a[0], bfr[0][1], acc1, 0, 0, 0);
    acc1 = __builtin_amdgcn_mfma_f32_16x16x32_bf16(a[1], bfr[1][1], acc1, 0, 0, 0);

    #pragma unroll
    for (int r = 0; r < 4; ++r) {
        unsigned lo = bf16u(leaky(acc0[r], 0.1f));
        unsigned hi = bf16u(leaky(acc1[r], 0.1f));
        h2[(long)(wavebase + 4 * g + r) * 16 + n] = (hi << 16) | lo;
    }
}

// ---------------- K2: edge phase + output GEMV, fused, MFMA ------------------
// = R13 body exactly (depth-2 pipeline, MFMA column-select conv reduce, no nt).
// ONLY change: XCD-chunked blockIdx swizzle. Round-robin dispatch maps block i
// to XCD i%8; remap so XCD k processes the contiguous point chunk k. Each
// XCD's h2 gather footprint then spans ONE batch (4.2 MB ~ L2-resident)
// instead of both (8.4 MB thrash). nblk = P/32 = 4096, divisible by 8.
__global__ __launch_bounds__(128) __attribute__((amdgpu_waves_per_eu(1, 4)))
void edgeout_mfma(
    const float* __restrict__ x, const float4* __restrict__ pos4,
    const int* __restrict__ nbr, const unsigned* __restrict__ h2,
    const float* __restrict__ Wa, const float* __restrict__ ba,
    const float* __restrict__ Wb, const float* __restrict__ bb,
    const short* __restrict__ pk, const float* __restrict__ bout,
    const float* __restrict__ bsc, float* __restrict__ out,
    int N, int P, int nblk)
{
    __shared__ float cbuf[2][32 * 17];     // per-wave conv, transposed [ch][pt]

    // ---- XCD-chunked swizzle (bijective: nblk % 8 == 0) ----
    int cpx = nblk >> 3;                       // blocks per XCD chunk
    int ebid = (blockIdx.x & 7) * cpx + (blockIdx.x >> 3);

    int tid = threadIdx.x;
    int lane = tid & 63;
    int widx = __builtin_amdgcn_readfirstlane(tid >> 6);
    int n = lane & 15, g = lane >> 4;
    int wavebase = (ebid * 2 + widx) * 16;
    if (wavebase >= P) return;
    long pbase = (wavebase >= N) ? (long)N : 0;

    // ---- loop-invariant per-lane preloads ----
    float waX[8], waY[8], waZ[8], bav[8];
    #pragma unroll
    for (int e = 0; e < 8; ++e) {
        int k = 8 * g + e;
        waX[e] = Wa[k]; waY[e] = Wa[HID + k]; waZ[e] = Wa[2 * HID + k];
        bav[e] = ba[k];
    }
    short8 wb0, wb1;
    #pragma unroll
    for (int e = 0; e < 8; ++e) {
        int k = 8 * g + e;
        wb0[e] = bf16s(Wb[k * HID + n]);
        wb1[e] = bf16s(Wb[k * HID + 16 + n]);
    }
    float bb0 = bb[n], bb1 = bb[16 + n];
    float* cb = cbuf[widx];

    // ---- GEMV x-row prefetch ----
    const float* xr = x + (long)(wavebase + n) * IN_C;
    float4 u0 = *(const float4*)(xr + 8 * g);
    float4 u1 = *(const float4*)(xr + 8 * g + 4);
    float4 u2 = *(const float4*)(xr + 32 + 8 * g);
    float4 u3 = *(const float4*)(xr + 32 + 8 * g + 4);

    // ---- conv accumulators: D col = point, row = channel ----
    f32x4 cacc0 = { 0.f, 0.f, 0.f, 0.f };   // channels 4g+r
    f32x4 cacc1 = { 0.f, 0.f, 0.f, 0.f };   // channels 16+4g+r

    // ---- edge phase: 16 points, software-pipelined, fully unrolled ----
    int4  qv[KNB]; int qs[KNB];
    float4 pp[KNB], pq[KNB];
    unsigned hv[KNB][4];

#define IDX(i) {                                                        \
        const int* nr = nbr + (long)(wavebase + (i)) * KNB;             \
        qv[i] = *(const int4*)(nr + 4 * g);                             \
        qs[i] = nr[n]; }
#define GATHER(i) {                                                     \
        pp[i] = pos4[wavebase + (i)];                                   \
        pq[i] = pos4[pbase + qs[i]];                                    \
        hv[i][0] = h2[(pbase + qv[i].x) * 16 + n];                      \
        hv[i][1] = h2[(pbase + qv[i].y) * 16 + n];                      \
        hv[i][2] = h2[(pbase + qv[i].z) * 16 + n];                      \
        hv[i][3] = h2[(pbase + qv[i].w) * 16 + n]; }

    #pragma unroll
    for (int pt = 0; pt < KNB; ++pt) {
        if (pt == 0) { IDX(0) IDX(1) IDX(2) GATHER(0) GATHER(1) }
        if (pt + 3 < KNB) IDX(pt + 3)
        if (pt + 2 < KNB) GATHER(pt + 2)

        float rx = pp[pt].x - pq[pt].x;
        float ry = pp[pt].y - pq[pt].y;
        float rz = pp[pt].z - pq[pt].z;

        short8 af;
        #pragma unroll
        for (int e = 0; e < 8; ++e) {
            float tv = fmaf(rx, waX[e], fmaf(ry, waY[e], fmaf(rz, waZ[e], bav[e])));
            af[e] = bf16s(leaky(tv, 0.1f));
        }

        f32x4 w0 = { bb0, bb0, bb0, bb0 };
        f32x4 w1 = { bb1, bb1, bb1, bb1 };
        w0 = __builtin_amdgcn_mfma_f32_16x16x32_bf16(af, wb0, w0, 0, 0, 0);
        w1 = __builtin_amdgcn_mfma_f32_16x16x32_bf16(af, wb1, w1, 0, 0, 0);

        float hA0 = __uint_as_float(hv[pt][0] << 16), hB0 = __uint_as_float(hv[pt][0] & 0xffff0000u);
        float hA1 = __uint_as_float(hv[pt][1] << 16), hB1 = __uint_as_float(hv[pt][1] & 0xffff0000u);
        float hA2 = __uint_as_float(hv[pt][2] << 16), hB2 = __uint_as_float(hv[pt][2] & 0xffff0000u);
        float hA3 = __uint_as_float(hv[pt][3] << 16), hB3 = __uint_as_float(hv[pt][3] & 0xffff0000u);

        // A-frags: products to bf16, k-slots e=0..3; e=4..7 zero
        short8 am0 = { bf16s(w0[0] * hA0), bf16s(w0[1] * hA1),
                       bf16s(w0[2] * hA2), bf16s(w0[3] * hA3), 0, 0, 0, 0 };
        short8 am1 = { bf16s(w1[0] * hB0), bf16s(w1[1] * hB1),
                       bf16s(w1[2] * hB2), bf16s(w1[3] * hB3), 0, 0, 0, 0 };

        // one-hot B: 1.0 (bf16 0x3F80) in k-slots 0..3 where col n == pt
        short sv = (n == pt) ? (short)0x3F80 : (short)0;
        short8 bsel = { sv, sv, sv, sv, 0, 0, 0, 0 };

        cacc0 = __builtin_amdgcn_mfma_f32_16x16x32_bf16(am0, bsel, cacc0, 0, 0, 0);
        cacc1 = __builtin_amdgcn_mfma_f32_16x16x32_bf16(am1, bsel, cacc1, 0, 0, 0);
    }
#undef IDX
#undef GATHER

    // dump conv to transposed LDS: lane (n,g) reg r -> conv[ch 4g+r][pt n]
    #pragma unroll
    for (int r = 0; r < 4; ++r) {
        cb[(4 * g + r) * 17 + n]      = cacc0[r];
        cb[(16 + 4 * g + r) * 17 + n] = cacc1[r];
    }
    asm volatile("s_waitcnt lgkmcnt(0)" ::: "memory");

    // ---- GEMV phase ----
    short8 a0, a1, a2;
    #pragma unroll
    for (int e = 0; e < 8; ++e)
        a0[e] = bf16s(cb[(8 * g + e) * 17 + n]);   // conv channels (k-step 0)
    a1[0] = bf16s(u0.x); a1[1] = bf16s(u0.y); a1[2] = bf16s(u0.z); a1[3] = bf16s(u0.w);
    a1[4] = bf16s(u1.x); a1[5] = bf16s(u1.y); a1[6] = bf16s(u1.z); a1[7] = bf16s(u1.w);
    a2[0] = bf16s(u2.x); a2[1] = bf16s(u2.y); a2[2] = bf16s(u2.z); a2[3] = bf16s(u2.w);
    a2[4] = bf16s(u3.x); a2[5] = bf16s(u3.y); a2[6] = bf16s(u3.z); a2[7] = bf16s(u3.w);

    #pragma unroll 2
    for (int nt = 0; nt < 8; ++nt) {
        short8 b0 = *(const short8*)(pk + ((long)(0 * 8 + nt) * 64 + lane) * 8);
        short8 b1 = *(const short8*)(pk + ((long)(1 * 8 + nt) * 64 + lane) * 8);
        short8 b2 = *(const short8*)(pk + ((long)(2 * 8 + nt) * 64 + lane) * 8);
        int o = nt * 16 + n;
        float bv = bout[o] + bsc[o];
        f32x4 acc = { bv, bv, bv, bv };
        acc = __builtin_amdgcn_mfma_f32_16x16x32_bf16(a0, b0, acc, 0, 0, 0);
        acc = __builtin_amdgcn_mfma_f32_16x16x32_bf16(a1, b1, acc, 0, 0, 0);
        acc = __builtin_amdgcn_mfma_f32_16x16x32_bf16(a2, b2, acc, 0, 0, 0);
        #pragma unroll
        for (int r = 0; r < 4; ++r)
            out[(long)(wavebase + 4 * g + r) * OUT_C + o] = leaky(acc[r], 0.01f);
    }
}

extern "C" void kernel_launch(void* const* d_in, const int* in_sizes, int n_in,
                              void* d_out, int out_size, void* d_ws, size_t ws_size,
                              hipStream_t stream) {
    const float* x    = (const float*)d_in[0];
    const float* pos  = (const float*)d_in[1];
    const int*   nbr  = (const int*)d_in[2];
    const float* Win  = (const float*)d_in[3];
    const float* bin  = (const float*)d_in[4];
    const float* Wa   = (const float*)d_in[5];
    const float* ba   = (const float*)d_in[6];
    const float* Wb   = (const float*)d_in[7];
    const float* bb   = (const float*)d_in[8];
    const float* Wout = (const float*)d_in[9];
    const float* bout = (const float*)d_in[10];
    const float* Wsc  = (const float*)d_in[11];
    const float* bsc  = (const float*)d_in[12];
    float* out = (float*)d_out;

    int P = in_sizes[0] / IN_C;   // B*N = 131072
    int N = P / 2;                // B = 2 per reference

    // ws layout: h2 [P*16 u32] | pos4 [P float4] | pk [1536*8 shorts]
    unsigned* h2  = (unsigned*)d_ws;
    float4*  pos4 = (float4*)((char*)d_ws + (size_t)P * 64);
    short*   pk   = (short*)((char*)d_ws + (size_t)P * 64 + (size_t)P * 16);

    hid_mfma<<<(P + 63) / 64, 256, 0, stream>>>(
        x, Win, bin, pos, Wout, Wsc, h2, pos4, pk, P);
    int nblk = (P + 31) / 32;     // 4096: divisible by 8 -> bijective swizzle
    edgeout_mfma<<<nblk, 128, 0, stream>>>(
        x, pos4, nbr, h2, Wa, ba, Wb, bb, pk, bout, bsc, out, N, P, nblk);
}